// Round 4
// baseline (950.055 us; speedup 1.0000x reference)
//
#include <hip/hip_runtime.h>

// ---------------------------------------------------------------------------
// GCN forward, CSR-gather aggregation + bf16-split MFMA GEMM.
//   per layer: H = X @ W            (MFMA, x=hi+lo bf16 split, 3 products)
//              AGG[d] = act(dinv[d]^2*H[d] + sum_e w_e*H[src_e] + b)
// Aggregate uses float4/half-wave gather: 2 edges per load instruction.
// Output: y[512*10] ++ global_mean[512*128], fp32.
// ---------------------------------------------------------------------------

#define ATOMIC_ADD_F32(p, v) __hip_atomic_fetch_add((p), (v), __ATOMIC_RELAXED, __HIP_MEMORY_SCOPE_AGENT)

constexpr int NG = 512;   // NUM_GRAPHS

typedef short short8 __attribute__((ext_vector_type(8)));
typedef float f32x4 __attribute__((ext_vector_type(4)));

__device__ __forceinline__ unsigned short f2bf(float x) {
    union { float f; unsigned u; } c; c.f = x;
    unsigned u = c.u + 0x7fffu + ((c.u >> 16) & 1u);   // RNE
    return (unsigned short)(u >> 16);
}
__device__ __forceinline__ float bf2f(unsigned short h) {
    union { unsigned u; float f; } c; c.u = ((unsigned)h) << 16;
    return c.f;
}

// --- degree ---------------------------------------------------------------
__global__ __launch_bounds__(256) void k_deg_init(int* __restrict__ deg, int N) {
    int i = blockIdx.x * 256 + threadIdx.x;
    if (i < N) deg[i] = 1;   // self-loop
}

__global__ __launch_bounds__(256) void k_deg_count(const int* __restrict__ dst,
                                                   int* __restrict__ deg, int E) {
    int i = blockIdx.x * 256 + threadIdx.x;
    int stride = gridDim.x * 256;
    for (; i < E; i += stride) atomicAdd(&deg[dst[i]], 1);
}

__global__ __launch_bounds__(256) void k_dinv(const int* __restrict__ deg,
                                              float* __restrict__ dinv, int N) {
    int i = blockIdx.x * 256 + threadIdx.x;
    if (i < N) dinv[i] = rsqrtf((float)deg[i]);
}

// --- exclusive scan of (deg[i]-1) -> rowptr[N+1] ----------------------------
__global__ __launch_bounds__(256) void k_scan_local(const int* __restrict__ deg,
                                                    int* __restrict__ rowptr,
                                                    int* __restrict__ partials, int N) {
    __shared__ int s[256];
    int t = threadIdx.x;
    int i = blockIdx.x * 256 + t;
    int v = (i < N) ? (deg[i] - 1) : 0;
    s[t] = v;
    __syncthreads();
#pragma unroll
    for (int off = 1; off < 256; off <<= 1) {
        int add = (t >= off) ? s[t - off] : 0;
        __syncthreads();
        s[t] += add;
        __syncthreads();
    }
    if (i < N) rowptr[i] = s[t] - v;
    if (t == 255) partials[blockIdx.x] = s[t];
}

__global__ __launch_bounds__(512) void k_scan_partials(int* __restrict__ partials, int nblk) {
    __shared__ int s[512];
    int t = threadIdx.x;
    int v = (t < nblk) ? partials[t] : 0;
    s[t] = v;
    __syncthreads();
#pragma unroll
    for (int off = 1; off < 512; off <<= 1) {
        int add = (t >= off) ? s[t - off] : 0;
        __syncthreads();
        s[t] += add;
        __syncthreads();
    }
    if (t < nblk) partials[t] = s[t] - v;
}

__global__ __launch_bounds__(256) void k_scan_apply(const int* __restrict__ deg,
                                                    int* __restrict__ rowptr,
                                                    const int* __restrict__ partials, int N) {
    int i = blockIdx.x * 256 + threadIdx.x;
    if (i < N) {
        int r = rowptr[i] + partials[blockIdx.x];
        rowptr[i] = r;
        if (i == N - 1) rowptr[N] = r + deg[i] - 1;
    }
}

// --- CSR fill: bucket edge sources by dst (src only; weights in 2nd pass) ----
__global__ __launch_bounds__(256) void k_csr_fill(const int* __restrict__ src,
                                                  const int* __restrict__ dst,
                                                  int* __restrict__ cursor,
                                                  int* __restrict__ csr_src, int E) {
    int i = blockIdx.x * 256 + threadIdx.x;
    int stride = gridDim.x * 256;
    for (; i < E; i += stride) {
        int d = dst[i];
        int pos = atomicAdd(&cursor[d], 1);
        csr_src[pos] = src[i];
    }
}

// --- CSR weights: linear pass, one thread per dst node -----------------------
__global__ __launch_bounds__(256) void k_csr_weights(const int* __restrict__ csr_src,
                                                     const int* __restrict__ rowptr,
                                                     const float* __restrict__ dinv,
                                                     float* __restrict__ csr_w, int N) {
    int d = blockIdx.x * 256 + threadIdx.x;
    if (d >= N) return;
    int beg = rowptr[d], end = rowptr[d + 1];
    float dd = dinv[d];
    for (int j = beg; j < end; ++j)
        csr_w[j] = dinv[csr_src[j]] * dd;
}

// --- W prep: split fp32 W[k][c] into transposed bf16 hi/lo: Wt[c][k] ---------
__global__ __launch_bounds__(256) void k_wsplit(const float* __restrict__ W,
                                                unsigned short* __restrict__ Wth,
                                                unsigned short* __restrict__ Wtl) {
    int idx = blockIdx.x * 256 + threadIdx.x;   // 16384 total
    int k = idx >> 7, c = idx & 127;
    float w = W[idx];
    unsigned short hi = f2bf(w);
    float lo = w - bf2f(hi);
    Wth[c * 128 + k] = hi;
    Wtl[c * 128 + k] = f2bf(lo);
}

// --- GEMM: H = X @ W via bf16-split MFMA (3 products), no LDS ----------------
__global__ __launch_bounds__(256) void k_gemm_mfma(const float* __restrict__ X,
                                                   const unsigned short* __restrict__ Wth,
                                                   const unsigned short* __restrict__ Wtl,
                                                   float* __restrict__ H, int N) {
    const int tid = threadIdx.x;
    const int wave = tid >> 6;
    const int l = tid & 63;
    const int wrow = wave & 1;
    const int wcol = wave >> 1;
    const int lr = l & 15;
    const int lkb = (l >> 4) * 8;

    const int row_base = blockIdx.x * 64 + wrow * 32;
    const int c_base = wcol * 64;

    f32x4 acc[2][4];
#pragma unroll
    for (int rt = 0; rt < 2; ++rt)
#pragma unroll
        for (int ct = 0; ct < 4; ++ct) acc[rt][ct] = (f32x4){0.f, 0.f, 0.f, 0.f};

#pragma unroll
    for (int ks = 0; ks < 4; ++ks) {
        const int koff = ks * 32 + lkb;

        short8 bh[4], bl[4];
#pragma unroll
        for (int ct = 0; ct < 4; ++ct) {
            size_t off = (size_t)(c_base + ct * 16 + lr) * 128 + koff;
            bh[ct] = *(const short8*)(Wth + off);
            bl[ct] = *(const short8*)(Wtl + off);
        }

        short8 ah[2], al[2];
#pragma unroll
        for (int rt = 0; rt < 2; ++rt) {
            int r = row_base + rt * 16 + lr;
            if (r >= N) r = N - 1;
            const float* xp = X + (size_t)r * 128 + koff;
            float4 f0 = *(const float4*)xp;
            float4 f1 = *(const float4*)(xp + 4);
            float xs[8] = {f0.x, f0.y, f0.z, f0.w, f1.x, f1.y, f1.z, f1.w};
            short8 h, lo;
#pragma unroll
            for (int j = 0; j < 8; ++j) {
                unsigned short hb = f2bf(xs[j]);
                float rem = xs[j] - bf2f(hb);
                h[j] = (short)hb;
                lo[j] = (short)f2bf(rem);
            }
            ah[rt] = h;
            al[rt] = lo;
        }

#pragma unroll
        for (int rt = 0; rt < 2; ++rt)
#pragma unroll
            for (int ct = 0; ct < 4; ++ct) {
                acc[rt][ct] = __builtin_amdgcn_mfma_f32_16x16x32_bf16(ah[rt], bh[ct], acc[rt][ct], 0, 0, 0);
                acc[rt][ct] = __builtin_amdgcn_mfma_f32_16x16x32_bf16(al[rt], bh[ct], acc[rt][ct], 0, 0, 0);
                acc[rt][ct] = __builtin_amdgcn_mfma_f32_16x16x32_bf16(ah[rt], bl[ct], acc[rt][ct], 0, 0, 0);
            }
    }

#pragma unroll
    for (int rt = 0; rt < 2; ++rt) {
        int r0 = row_base + rt * 16 + (l >> 4) * 4;
#pragma unroll
        for (int ct = 0; ct < 4; ++ct) {
            int col = c_base + ct * 16 + lr;
#pragma unroll
            for (int j = 0; j < 4; ++j) {
                int r = r0 + j;
                if (r < N) H[(size_t)r * 128 + col] = acc[rt][ct][j];
            }
        }
    }
}

// --- aggregate (CSR gather): one wave per dst node ---------------------------
// float4/half-wave: lanes 0-31 handle even edges, 32-63 odd edges.
// AGG[d] = act( dinv[d]^2*H[d] + sum_j csr_w[j]*H[csr_src[j]] + bias )
__global__ __launch_bounds__(256) void k_aggregate(const int* __restrict__ csr_src,
                                                   const float* __restrict__ csr_w,
                                                   const int* __restrict__ rowptr,
                                                   const float* __restrict__ dinv,
                                                   const float* __restrict__ H,
                                                   const float* __restrict__ bias,
                                                   float* __restrict__ AGG,
                                                   int N, int use_act) {
    int d = blockIdx.x * 4 + (threadIdx.x >> 6);
    if (d >= N) return;
    const int lane = threadIdx.x & 63;
    const int half = lane >> 5;     // even/odd edge stream
    const int il = lane & 31;       // feature group: floats il*4 .. il*4+3

    int beg = rowptr[d], end = rowptr[d + 1];
    float4 acc = make_float4(0.f, 0.f, 0.f, 0.f);

    int cnt = end - beg;
    int jfull = beg + (cnt & ~15);
    int j = beg;
    for (; j < jfull; j += 16) {
        int s[8]; float w[8]; float4 v[8];
#pragma unroll
        for (int u = 0; u < 8; ++u) {
            int idx = j + 2 * u + half;
            s[u] = csr_src[idx];
            w[u] = csr_w[idx];
        }
#pragma unroll
        for (int u = 0; u < 8; ++u)
            v[u] = ((const float4*)(H + (size_t)s[u] * 128))[il];
#pragma unroll
        for (int u = 0; u < 8; ++u) {
            acc.x = fmaf(w[u], v[u].x, acc.x);
            acc.y = fmaf(w[u], v[u].y, acc.y);
            acc.z = fmaf(w[u], v[u].z, acc.z);
            acc.w = fmaf(w[u], v[u].w, acc.w);
        }
    }
    // tail (< 16 edges)
#pragma unroll
    for (int u = 0; u < 8; ++u) {
        int idx = j + 2 * u + half;
        if (idx < end) {
            int s = csr_src[idx];
            float w = csr_w[idx];
            float4 v = ((const float4*)(H + (size_t)s * 128))[il];
            acc.x = fmaf(w, v.x, acc.x);
            acc.y = fmaf(w, v.y, acc.y);
            acc.z = fmaf(w, v.z, acc.z);
            acc.w = fmaf(w, v.w, acc.w);
        }
    }

    // combine even/odd halves (all lanes end with the full sum)
    acc.x += __shfl_xor(acc.x, 32);
    acc.y += __shfl_xor(acc.y, 32);
    acc.z += __shfl_xor(acc.z, 32);
    acc.w += __shfl_xor(acc.w, 32);

    if (half == 0) {
        float dd = dinv[d];
        float sw = dd * dd;
        float4 sv = ((const float4*)(H + (size_t)d * 128))[il];
        acc.x = fmaf(sw, sv.x, acc.x);
        acc.y = fmaf(sw, sv.y, acc.y);
        acc.z = fmaf(sw, sv.z, acc.z);
        acc.w = fmaf(sw, sv.w, acc.w);
        if (use_act) {
            float4 b4 = ((const float4*)bias)[il];
            acc.x = fmaxf(acc.x + b4.x, 0.f);
            acc.y = fmaxf(acc.y + b4.y, 0.f);
            acc.z = fmaxf(acc.z + b4.z, 0.f);
            acc.w = fmaxf(acc.w + b4.w, 0.f);
        }
        ((float4*)(AGG + (size_t)d * 128))[il] = acc;
    }
}

// --- pool: pooled[g] += relu(AGG[i] + b) for batch[i]==g (batch sorted) -----
__global__ __launch_bounds__(128) void k_pool(const float* __restrict__ H,
                                              const float* __restrict__ b,
                                              const int* __restrict__ batch,
                                              float* __restrict__ pooled,
                                              float* __restrict__ counts, int N) {
    int k = threadIdx.x;
    int i0 = blockIdx.x * 64;
    if (i0 >= N) return;
    int iend = min(i0 + 64, N);
    float bk = b[k];
    float acc = 0.f;
    int cnt = 0;
    int cur = batch[i0];
    for (int i = i0; i < iend; ++i) {
        int g = batch[i];
        if (g != cur) {
            ATOMIC_ADD_F32(&pooled[cur * 128 + k], acc);
            if (k == 0) ATOMIC_ADD_F32(&counts[cur], (float)cnt);
            acc = 0.f; cnt = 0; cur = g;
        }
        acc += fmaxf(H[(size_t)i * 128 + k] + bk, 0.f);
        cnt++;
    }
    ATOMIC_ADD_F32(&pooled[cur * 128 + k], acc);
    if (k == 0) ATOMIC_ADD_F32(&counts[cur], (float)cnt);
}

// --- finalize: global_mean + head -------------------------------------------
__global__ __launch_bounds__(128) void k_finalize(const float* __restrict__ pooled,
                                                  const float* __restrict__ counts,
                                                  const float* __restrict__ Wl,
                                                  const float* __restrict__ bl,
                                                  float* __restrict__ out) {
    int g = blockIdx.x;
    int t = threadIdx.x;
    __shared__ float m[128];
    float c = fmaxf(counts[g], 1.f);
    float mean = pooled[g * 128 + t] / c;
    out[NG * 10 + g * 128 + t] = mean;
    m[t] = mean;
    __syncthreads();
    if (t < 10) {
        float acc = bl[t];
#pragma unroll 16
        for (int k = 0; k < 128; ++k) acc = fmaf(m[k], Wl[k * 10 + t], acc);
        out[g * 10 + t] = acc;
    }
}

// ---------------------------------------------------------------------------
extern "C" void kernel_launch(void* const* d_in, const int* in_sizes, int n_in,
                              void* d_out, int out_size, void* d_ws, size_t ws_size,
                              hipStream_t stream) {
    const float* x     = (const float*)d_in[0];
    const int*   ei    = (const int*)d_in[1];
    const int*   batch = (const int*)d_in[2];
    const float* Wt[4] = { (const float*)d_in[3], (const float*)d_in[5],
                           (const float*)d_in[7], (const float*)d_in[9] };
    const float* bt[4] = { (const float*)d_in[4], (const float*)d_in[6],
                           (const float*)d_in[8], (const float*)d_in[10] };
    const float* Wl = (const float*)d_in[11];
    const float* bl = (const float*)d_in[12];
    float* out = (float*)d_out;

    const int N = in_sizes[0] / 128;
    const int E = in_sizes[1] / 2;
    const int* src = ei;
    const int* dst = ei + E;

    // workspace layout
    char* p = (char*)d_ws;
    float* H       = (float*)p;  p += (size_t)N * 128 * 4;
    float* AGG     = (float*)p;  p += (size_t)N * 128 * 4;
    float* dinv    = (float*)p;  p += (size_t)N * 4;
    int*   deg     = (int*)p;    p += (size_t)N * 4;
    int*   rowptr  = (int*)p;    p += (size_t)(N + 1) * 4;
    int*   cursor  = (int*)p;    p += (size_t)N * 4;
    int*   csr_src = (int*)p;    p += (size_t)E * 4;
    float* csr_w   = (float*)p;  p += (size_t)E * 4;
    int*   partials= (int*)p;    p += 512 * 4;
    float* pooled  = (float*)p;  p += (size_t)NG * 128 * 4;
    float* counts  = (float*)p;  p += (size_t)NG * 4;
    unsigned short* Wsp = (unsigned short*)p; p += 4 * 2 * 128 * 128 * 2;

    const int nblk = (N + 255) / 256;

    // degrees + norms
    k_deg_init<<<nblk, 256, 0, stream>>>(deg, N);
    k_deg_count<<<1024, 256, 0, stream>>>(dst, deg, E);
    k_dinv<<<nblk, 256, 0, stream>>>(deg, dinv, N);

    // CSR build (by dst)
    k_scan_local<<<nblk, 256, 0, stream>>>(deg, rowptr, partials, N);
    k_scan_partials<<<1, 512, 0, stream>>>(partials, nblk);
    k_scan_apply<<<nblk, 256, 0, stream>>>(deg, rowptr, partials, N);
    hipMemcpyAsync(cursor, rowptr, (size_t)N * 4, hipMemcpyDeviceToDevice, stream);
    k_csr_fill<<<1024, 256, 0, stream>>>(src, dst, cursor, csr_src, E);
    k_csr_weights<<<nblk, 256, 0, stream>>>(csr_src, rowptr, dinv, csr_w, N);

    // W splits (hi/lo bf16, transposed)
    unsigned short* Wth[4]; unsigned short* Wtl[4];
    for (int l = 0; l < 4; ++l) {
        Wth[l] = Wsp + (size_t)l * 2 * 16384;
        Wtl[l] = Wth[l] + 16384;
        k_wsplit<<<64, 256, 0, stream>>>(Wt[l], Wth[l], Wtl[l]);
    }

    // layers
    const int gemm_blocks = (N + 63) / 64;
    const int agg_blocks = (N + 3) / 4;
    const float* in = x;
    for (int l = 0; l < 4; ++l) {
        k_gemm_mfma<<<gemm_blocks, 256, 0, stream>>>(in, Wth[l], Wtl[l], H, N);
        k_aggregate<<<agg_blocks, 256, 0, stream>>>(csr_src, csr_w, rowptr, dinv, H,
                                                    bt[l], AGG, N, (l < 3) ? 1 : 0);
        in = AGG;
    }

    // pool + head
    hipMemsetAsync(pooled, 0, (size_t)(NG * 128 + NG) * 4, stream);
    k_pool<<<(N + 63) / 64, 128, 0, stream>>>(AGG, bt[3], batch, pooled, counts, N);
    k_finalize<<<NG, 128, 0, stream>>>(pooled, counts, Wl, bl, out);
}

// Round 5
// 750.712 us; speedup vs baseline: 1.2655x; 1.2655x over previous
//
#include <hip/hip_runtime.h>

// ---------------------------------------------------------------------------
// GCN forward, fp16 datapath.
//   prep:  deg/dinv, CSR(dst)->src only, W -> fp16 hi/lo (lo scaled 2^12),
//          X -> fp16.
//   layer: H' = dinv[r] * (A @ W)        (f16 MFMA, 2 products, split acc)
//          A_next[d] = relu( dinv[d]*(sum_{s in N(d)} H'[s] + H'[d]) + b )
//   pool:  mean over sorted batch ids (fp16 in), then 128->10 head.
// Output: y[512*10] ++ global_mean[512*128], fp32.
// ---------------------------------------------------------------------------

#define ATOMIC_ADD_F32(p, v) __hip_atomic_fetch_add((p), (v), __ATOMIC_RELAXED, __HIP_MEMORY_SCOPE_AGENT)

constexpr int NG = 512;   // NUM_GRAPHS
constexpr float LO_SCALE = 4096.f;      // 2^12
constexpr float LO_INV   = 1.f / 4096.f;

typedef _Float16 half8 __attribute__((ext_vector_type(8)));
typedef _Float16 half4 __attribute__((ext_vector_type(4)));
typedef float f32x4 __attribute__((ext_vector_type(4)));

// --- degree ---------------------------------------------------------------
__global__ __launch_bounds__(256) void k_deg_init(int* __restrict__ deg, int N) {
    int i = blockIdx.x * 256 + threadIdx.x;
    if (i < N) deg[i] = 1;   // self-loop
}

__global__ __launch_bounds__(256) void k_deg_count(const int* __restrict__ dst,
                                                   int* __restrict__ deg, int E) {
    int i = blockIdx.x * 256 + threadIdx.x;
    int stride = gridDim.x * 256;
    for (; i < E; i += stride) atomicAdd(&deg[dst[i]], 1);
}

__global__ __launch_bounds__(256) void k_dinv(const int* __restrict__ deg,
                                              float* __restrict__ dinv, int N) {
    int i = blockIdx.x * 256 + threadIdx.x;
    if (i < N) dinv[i] = rsqrtf((float)deg[i]);
}

// --- exclusive scan of (deg[i]-1) -> rowptr[N+1] ----------------------------
__global__ __launch_bounds__(256) void k_scan_local(const int* __restrict__ deg,
                                                    int* __restrict__ rowptr,
                                                    int* __restrict__ partials, int N) {
    __shared__ int s[256];
    int t = threadIdx.x;
    int i = blockIdx.x * 256 + t;
    int v = (i < N) ? (deg[i] - 1) : 0;
    s[t] = v;
    __syncthreads();
#pragma unroll
    for (int off = 1; off < 256; off <<= 1) {
        int add = (t >= off) ? s[t - off] : 0;
        __syncthreads();
        s[t] += add;
        __syncthreads();
    }
    if (i < N) rowptr[i] = s[t] - v;
    if (t == 255) partials[blockIdx.x] = s[t];
}

__global__ __launch_bounds__(512) void k_scan_partials(int* __restrict__ partials, int nblk) {
    __shared__ int s[512];
    int t = threadIdx.x;
    int v = (t < nblk) ? partials[t] : 0;
    s[t] = v;
    __syncthreads();
#pragma unroll
    for (int off = 1; off < 512; off <<= 1) {
        int add = (t >= off) ? s[t - off] : 0;
        __syncthreads();
        s[t] += add;
        __syncthreads();
    }
    if (t < nblk) partials[t] = s[t] - v;
}

__global__ __launch_bounds__(256) void k_scan_apply(const int* __restrict__ deg,
                                                    int* __restrict__ rowptr,
                                                    const int* __restrict__ partials, int N) {
    int i = blockIdx.x * 256 + threadIdx.x;
    if (i < N) {
        int r = rowptr[i] + partials[blockIdx.x];
        rowptr[i] = r;
        if (i == N - 1) rowptr[N] = r + deg[i] - 1;
    }
}

// --- CSR fill: bucket edge sources by dst ------------------------------------
__global__ __launch_bounds__(256) void k_csr_fill(const int* __restrict__ src,
                                                  const int* __restrict__ dst,
                                                  int* __restrict__ cursor,
                                                  int* __restrict__ csr_src, int E) {
    int i = blockIdx.x * 256 + threadIdx.x;
    int stride = gridDim.x * 256;
    for (; i < E; i += stride) {
        int d = dst[i];
        int pos = atomicAdd(&cursor[d], 1);
        csr_src[pos] = src[i];
    }
}

// --- W prep: W[k][c] fp32 -> transposed fp16 hi + scaled lo: Wt[c][k] --------
__global__ __launch_bounds__(256) void k_wsplit(const float* __restrict__ W,
                                                _Float16* __restrict__ Wth,
                                                _Float16* __restrict__ Wtl) {
    int idx = blockIdx.x * 256 + threadIdx.x;   // 16384 total
    int k = idx >> 7, c = idx & 127;
    float w = W[idx];
    _Float16 hi = (_Float16)w;
    float lo = (w - (float)hi) * LO_SCALE;      // keep lo in fp16-normal range
    Wth[c * 128 + k] = hi;
    Wtl[c * 128 + k] = (_Float16)lo;
}

// --- X prep: fp32 -> fp16 -----------------------------------------------------
__global__ __launch_bounds__(256) void k_xhalf(const float* __restrict__ X,
                                               _Float16* __restrict__ Xh, int total) {
    int i = (blockIdx.x * 256 + threadIdx.x) * 4;
    if (i < total) {
        float4 v = *(const float4*)(X + i);
        half4 h = { (_Float16)v.x, (_Float16)v.y, (_Float16)v.z, (_Float16)v.w };
        *(half4*)(Xh + i) = h;
    }
}

// --- GEMM: H' = dinv[r] * (A @ W), f16 MFMA, 2 products, split accumulator ---
// block 256 = 4 waves: wave (wrow=wave&1 -> 32 rows, wcol=wave>>1 -> 64 cols)
__global__ __launch_bounds__(256) void k_gemm_f16(const _Float16* __restrict__ A,
                                                  const _Float16* __restrict__ Wth,
                                                  const _Float16* __restrict__ Wtl,
                                                  const float* __restrict__ dinv,
                                                  _Float16* __restrict__ Hh, int N) {
    const int tid = threadIdx.x;
    const int wave = tid >> 6;
    const int l = tid & 63;
    const int wrow = wave & 1;
    const int wcol = wave >> 1;
    const int lr = l & 15;
    const int lkb = (l >> 4) * 8;

    const int row_base = blockIdx.x * 64 + wrow * 32;
    const int c_base = wcol * 64;

    f32x4 acch[2][4], accl[2][4];
#pragma unroll
    for (int rt = 0; rt < 2; ++rt)
#pragma unroll
        for (int ct = 0; ct < 4; ++ct) {
            acch[rt][ct] = (f32x4){0.f, 0.f, 0.f, 0.f};
            accl[rt][ct] = (f32x4){0.f, 0.f, 0.f, 0.f};
        }

#pragma unroll
    for (int ks = 0; ks < 4; ++ks) {
        const int koff = ks * 32 + lkb;

        half8 bh[4], bl[4];
#pragma unroll
        for (int ct = 0; ct < 4; ++ct) {
            size_t off = (size_t)(c_base + ct * 16 + lr) * 128 + koff;
            bh[ct] = *(const half8*)(Wth + off);
            bl[ct] = *(const half8*)(Wtl + off);
        }

        half8 a[2];
#pragma unroll
        for (int rt = 0; rt < 2; ++rt) {
            int r = row_base + rt * 16 + lr;
            if (r >= N) r = N - 1;                 // clamp; stores guarded
            a[rt] = *(const half8*)(A + (size_t)r * 128 + koff);
        }

#pragma unroll
        for (int rt = 0; rt < 2; ++rt)
#pragma unroll
            for (int ct = 0; ct < 4; ++ct) {
                acch[rt][ct] = __builtin_amdgcn_mfma_f32_16x16x32_f16(a[rt], bh[ct], acch[rt][ct], 0, 0, 0);
                accl[rt][ct] = __builtin_amdgcn_mfma_f32_16x16x32_f16(a[rt], bl[ct], accl[rt][ct], 0, 0, 0);
            }
    }

    // store: D frag: col = lane&15, row = (lane>>4)*4 + j ; scale by dinv[row]
#pragma unroll
    for (int rt = 0; rt < 2; ++rt) {
        int r0 = row_base + rt * 16 + (l >> 4) * 4;
        float dv[4];
#pragma unroll
        for (int j = 0; j < 4; ++j) dv[j] = (r0 + j < N) ? dinv[r0 + j] : 0.f;
#pragma unroll
        for (int ct = 0; ct < 4; ++ct) {
            int col = c_base + ct * 16 + lr;
#pragma unroll
            for (int j = 0; j < 4; ++j) {
                int r = r0 + j;
                if (r < N) {
                    float v = fmaf(accl[rt][ct][j], LO_INV, acch[rt][ct][j]);
                    Hh[(size_t)r * 128 + col] = (_Float16)(v * dv[j]);
                }
            }
        }
    }
}

// --- aggregate (CSR gather, fp16 rows): one wave per dst node -----------------
// A_next[d] = relu( dinv[d]*(sum_s H'[s] + H'[d]) + b )   (fp16 out)
__global__ __launch_bounds__(256) void k_aggregate_f16(const int* __restrict__ csr_src,
                                                       const int* __restrict__ rowptr,
                                                       const float* __restrict__ dinv,
                                                       const _Float16* __restrict__ Hh,
                                                       const float* __restrict__ bias,
                                                       _Float16* __restrict__ Ah, int N) {
    int d = blockIdx.x * 4 + (threadIdx.x >> 6);
    if (d >= N) return;
    const int lane = threadIdx.x & 63;
    const unsigned* Hu = (const unsigned*)Hh;        // 64 dwords per row

    int beg = rowptr[d], end = rowptr[d + 1];
    union PK { unsigned u; _Float16 h[2]; };

    // self term
    PK sv; sv.u = Hu[(size_t)d * 64 + lane];
    float ax = (float)sv.h[0];
    float ay = (float)sv.h[1];

    int j = beg;
    for (; j + 7 < end; j += 8) {
        int s[8]; PK v[8];
#pragma unroll
        for (int u = 0; u < 8; ++u) s[u] = csr_src[j + u];
#pragma unroll
        for (int u = 0; u < 8; ++u) v[u].u = Hu[(size_t)s[u] * 64 + lane];
#pragma unroll
        for (int u = 0; u < 8; ++u) {
            ax += (float)v[u].h[0];
            ay += (float)v[u].h[1];
        }
    }
    for (; j < end; ++j) {
        PK v; v.u = Hu[(size_t)csr_src[j] * 64 + lane];
        ax += (float)v.h[0];
        ay += (float)v.h[1];
    }

    float dd = dinv[d];
    float2 b2 = ((const float2*)bias)[lane];
    ax = fmaxf(fmaf(dd, ax, b2.x), 0.f);
    ay = fmaxf(fmaf(dd, ay, b2.y), 0.f);

    PK o; o.h[0] = (_Float16)ax; o.h[1] = (_Float16)ay;
    ((unsigned*)Ah)[(size_t)d * 64 + lane] = o.u;
}

// --- pool: pooled[g] += A[i] (bias+relu already applied), batch sorted --------
__global__ __launch_bounds__(128) void k_pool(const _Float16* __restrict__ A,
                                              const int* __restrict__ batch,
                                              float* __restrict__ pooled,
                                              float* __restrict__ counts, int N) {
    int k = threadIdx.x;
    int i0 = blockIdx.x * 64;
    if (i0 >= N) return;
    int iend = min(i0 + 64, N);
    float acc = 0.f;
    int cnt = 0;
    int cur = batch[i0];
    for (int i = i0; i < iend; ++i) {
        int g = batch[i];
        if (g != cur) {
            ATOMIC_ADD_F32(&pooled[cur * 128 + k], acc);
            if (k == 0) ATOMIC_ADD_F32(&counts[cur], (float)cnt);
            acc = 0.f; cnt = 0; cur = g;
        }
        acc += (float)A[(size_t)i * 128 + k];
        cnt++;
    }
    ATOMIC_ADD_F32(&pooled[cur * 128 + k], acc);
    if (k == 0) ATOMIC_ADD_F32(&counts[cur], (float)cnt);
}

// --- finalize: global_mean + head ---------------------------------------------
__global__ __launch_bounds__(128) void k_finalize(const float* __restrict__ pooled,
                                                  const float* __restrict__ counts,
                                                  const float* __restrict__ Wl,
                                                  const float* __restrict__ bl,
                                                  float* __restrict__ out) {
    int g = blockIdx.x;
    int t = threadIdx.x;
    __shared__ float m[128];
    float c = fmaxf(counts[g], 1.f);
    float mean = pooled[g * 128 + t] / c;
    out[NG * 10 + g * 128 + t] = mean;
    m[t] = mean;
    __syncthreads();
    if (t < 10) {
        float acc = bl[t];
#pragma unroll 16
        for (int k = 0; k < 128; ++k) acc = fmaf(m[k], Wl[k * 10 + t], acc);
        out[g * 10 + t] = acc;
    }
}

// ---------------------------------------------------------------------------
extern "C" void kernel_launch(void* const* d_in, const int* in_sizes, int n_in,
                              void* d_out, int out_size, void* d_ws, size_t ws_size,
                              hipStream_t stream) {
    const float* x     = (const float*)d_in[0];
    const int*   ei    = (const int*)d_in[1];
    const int*   batch = (const int*)d_in[2];
    const float* Wt[4] = { (const float*)d_in[3], (const float*)d_in[5],
                           (const float*)d_in[7], (const float*)d_in[9] };
    const float* bt[4] = { (const float*)d_in[4], (const float*)d_in[6],
                           (const float*)d_in[8], (const float*)d_in[10] };
    const float* Wl = (const float*)d_in[11];
    const float* bl = (const float*)d_in[12];
    float* out = (float*)d_out;

    const int N = in_sizes[0] / 128;
    const int E = in_sizes[1] / 2;
    const int* src = ei;
    const int* dst = ei + E;

    // workspace layout
    char* p = (char*)d_ws;
    _Float16* Xh    = (_Float16*)p;  p += (size_t)N * 128 * 2;
    _Float16* Hh    = (_Float16*)p;  p += (size_t)N * 128 * 2;
    _Float16* Ah    = (_Float16*)p;  p += (size_t)N * 128 * 2;
    float* dinv     = (float*)p;     p += (size_t)N * 4;
    int*   deg      = (int*)p;       p += (size_t)N * 4;
    int*   rowptr   = (int*)p;       p += (size_t)(N + 1) * 4;
    int*   cursor   = (int*)p;       p += (size_t)N * 4;
    int*   csr_src  = (int*)p;       p += (size_t)E * 4;
    int*   partials = (int*)p;       p += 512 * 4;
    float* pooled   = (float*)p;     p += (size_t)NG * 128 * 4;
    float* counts   = (float*)p;     p += (size_t)NG * 4;
    _Float16* Wsp   = (_Float16*)p;  p += 4 * 2 * 128 * 128 * 2;

    const int nblk = (N + 255) / 256;

    // degrees + norms
    k_deg_init<<<nblk, 256, 0, stream>>>(deg, N);
    k_deg_count<<<1024, 256, 0, stream>>>(dst, deg, E);
    k_dinv<<<nblk, 256, 0, stream>>>(deg, dinv, N);

    // CSR build (by dst)
    k_scan_local<<<nblk, 256, 0, stream>>>(deg, rowptr, partials, N);
    k_scan_partials<<<1, 512, 0, stream>>>(partials, nblk);
    k_scan_apply<<<nblk, 256, 0, stream>>>(deg, rowptr, partials, N);
    hipMemcpyAsync(cursor, rowptr, (size_t)N * 4, hipMemcpyDeviceToDevice, stream);
    k_csr_fill<<<1024, 256, 0, stream>>>(src, dst, cursor, csr_src, E);

    // weight splits + X cast
    _Float16* Wth[4]; _Float16* Wtl[4];
    for (int l = 0; l < 4; ++l) {
        Wth[l] = Wsp + (size_t)l * 2 * 16384;
        Wtl[l] = Wth[l] + 16384;
        k_wsplit<<<64, 256, 0, stream>>>(Wt[l], Wth[l], Wtl[l]);
    }
    k_xhalf<<<(N * 128 / 4 + 255) / 256, 256, 0, stream>>>(x, Xh, N * 128);

    // layers
    const int gemm_blocks = (N + 63) / 64;
    const int agg_blocks = (N + 3) / 4;
    const _Float16* in = Xh;
    for (int l = 0; l < 4; ++l) {
        k_gemm_f16<<<gemm_blocks, 256, 0, stream>>>(in, Wth[l], Wtl[l], dinv, Hh, N);
        k_aggregate_f16<<<agg_blocks, 256, 0, stream>>>(csr_src, rowptr, dinv, Hh, bt[l], Ah, N);
        in = Ah;
    }

    // pool + head
    hipMemsetAsync(pooled, 0, (size_t)(NG * 128 + NG) * 4, stream);
    k_pool<<<(N + 63) / 64, 128, 0, stream>>>(Ah, batch, pooled, counts, N);
    k_finalize<<<NG, 128, 0, stream>>>(pooled, counts, Wl, bl, out);
}

// Round 6
// 678.714 us; speedup vs baseline: 1.3998x; 1.1061x over previous
//
#include <hip/hip_runtime.h>

// ---------------------------------------------------------------------------
// GCN forward, fp16 datapath + XCD-partitioned CSR build.
//   prep:  deg/dinv, CSR(dst)->src (XCD-local scatter), W -> fp16 hi/lo,
//          X -> fp16.
//   layer: H' = dinv[r] * (A @ W)        (f16 MFMA, 2 products, split acc)
//          A_next[d] = relu( dinv[d]*(sum_{s in N(d)} H'[s] + H'[d]) + b )
//   pool:  mean over sorted batch ids (fp16 in), then 128->10 head.
// Output: y[512*10] ++ global_mean[512*128], fp32.
// ---------------------------------------------------------------------------

#define ATOMIC_ADD_F32(p, v) __hip_atomic_fetch_add((p), (v), __ATOMIC_RELAXED, __HIP_MEMORY_SCOPE_AGENT)

constexpr int NG = 512;   // NUM_GRAPHS
constexpr float LO_SCALE = 4096.f;      // 2^12
constexpr float LO_INV   = 1.f / 4096.f;

typedef _Float16 half8 __attribute__((ext_vector_type(8)));
typedef _Float16 half4 __attribute__((ext_vector_type(4)));
typedef float f32x4 __attribute__((ext_vector_type(4)));

// --- degree (XCD-partitioned histogram) --------------------------------------
__global__ __launch_bounds__(256) void k_deg_init(int* __restrict__ deg, int N) {
    int i = blockIdx.x * 256 + threadIdx.x;
    if (i < N) deg[i] = 1;   // self-loop
}

// range = blockIdx&7 (XCD heuristic), chunk = blockIdx>>3.
// Each block counts only dst in its node range -> histogram slice stays in
// one XCD's L2. Correct regardless of actual block->XCD mapping.
__global__ __launch_bounds__(256) void k_deg_count_xcd(const int* __restrict__ dst,
                                                       int* __restrict__ deg,
                                                       int E, int N) {
    const int range = blockIdx.x & 7;
    const int chunk = blockIdx.x >> 3;
    const int nchunks = gridDim.x >> 3;
    const int csz = (E + nchunks - 1) / nchunks;
    const int lo = chunk * csz;
    const int hi = min(lo + csz, E);
    const int nr = N / 8;
    const int rlo = range * nr;
    const int rhi = (range == 7) ? N : rlo + nr;
    for (int i = lo + threadIdx.x; i < hi; i += 256) {
        int d = dst[i];
        if (d >= rlo && d < rhi) atomicAdd(&deg[d], 1);
    }
}

// --- exclusive scan of (deg[i]-1) -> rowptr[N+1]; also dinv ------------------
__global__ __launch_bounds__(256) void k_scan_local(const int* __restrict__ deg,
                                                    int* __restrict__ rowptr,
                                                    int* __restrict__ partials,
                                                    float* __restrict__ dinv, int N) {
    __shared__ int s[256];
    int t = threadIdx.x;
    int i = blockIdx.x * 256 + t;
    int dg = (i < N) ? deg[i] : 1;
    if (i < N) dinv[i] = rsqrtf((float)dg);
    int v = (i < N) ? (dg - 1) : 0;
    s[t] = v;
    __syncthreads();
#pragma unroll
    for (int off = 1; off < 256; off <<= 1) {
        int add = (t >= off) ? s[t - off] : 0;
        __syncthreads();
        s[t] += add;
        __syncthreads();
    }
    if (i < N) rowptr[i] = s[t] - v;
    if (t == 255) partials[blockIdx.x] = s[t];
}

__global__ __launch_bounds__(512) void k_scan_partials(int* __restrict__ partials, int nblk) {
    __shared__ int s[512];
    int t = threadIdx.x;
    int v = (t < nblk) ? partials[t] : 0;
    s[t] = v;
    __syncthreads();
#pragma unroll
    for (int off = 1; off < 512; off <<= 1) {
        int add = (t >= off) ? s[t - off] : 0;
        __syncthreads();
        s[t] += add;
        __syncthreads();
    }
    if (t < nblk) partials[t] = s[t] - v;
}

// also seeds cursor = rowptr (kills the d2d memcpy)
__global__ __launch_bounds__(256) void k_scan_apply(const int* __restrict__ deg,
                                                    int* __restrict__ rowptr,
                                                    int* __restrict__ cursor,
                                                    const int* __restrict__ partials, int N) {
    int i = blockIdx.x * 256 + threadIdx.x;
    if (i < N) {
        int r = rowptr[i] + partials[blockIdx.x];
        rowptr[i] = r;
        cursor[i] = r;
        if (i == N - 1) rowptr[N] = r + deg[i] - 1;
    }
}

// --- CSR fill, XCD-partitioned -----------------------------------------------
// Writes for node range r land in a dense ~0.8MB slice of csr_src plus a
// 50KB cursor slice -> L2-resident on one XCD -> full-line writebacks.
__global__ __launch_bounds__(256) void k_csr_fill_xcd(const int* __restrict__ src,
                                                      const int* __restrict__ dst,
                                                      int* __restrict__ cursor,
                                                      int* __restrict__ csr_src,
                                                      int E, int N) {
    const int range = blockIdx.x & 7;
    const int chunk = blockIdx.x >> 3;
    const int nchunks = gridDim.x >> 3;
    const int csz = (E + nchunks - 1) / nchunks;
    const int lo = chunk * csz;
    const int hi = min(lo + csz, E);
    const int nr = N / 8;
    const int rlo = range * nr;
    const int rhi = (range == 7) ? N : rlo + nr;
    for (int i = lo + threadIdx.x; i < hi; i += 256) {
        int d = dst[i];
        if (d >= rlo && d < rhi) {
            int pos = atomicAdd(&cursor[d], 1);
            csr_src[pos] = src[i];
        }
    }
}

// --- W prep: all 4 layers in one launch ---------------------------------------
struct WSplitArgs {
    const float* W[4];
    _Float16* Wth[4];
    _Float16* Wtl[4];
};
__global__ __launch_bounds__(256) void k_wsplit4(WSplitArgs a) {
    int idx = blockIdx.x * 256 + threadIdx.x;   // 4 * 16384 total
    int layer = idx >> 14;
    int e = idx & 16383;
    int k = e >> 7, c = e & 127;
    float w = a.W[layer][e];
    _Float16 hi = (_Float16)w;
    float lo = (w - (float)hi) * LO_SCALE;
    a.Wth[layer][c * 128 + k] = hi;
    a.Wtl[layer][c * 128 + k] = (_Float16)lo;
}

// --- X prep: fp32 -> fp16 -----------------------------------------------------
__global__ __launch_bounds__(256) void k_xhalf(const float* __restrict__ X,
                                               _Float16* __restrict__ Xh, int total) {
    int i = (blockIdx.x * 256 + threadIdx.x) * 4;
    if (i < total) {
        float4 v = *(const float4*)(X + i);
        half4 h = { (_Float16)v.x, (_Float16)v.y, (_Float16)v.z, (_Float16)v.w };
        *(half4*)(Xh + i) = h;
    }
}

// --- GEMM: H' = dinv[r] * (A @ W), f16 MFMA, 2 products, split accumulator ---
__global__ __launch_bounds__(256) void k_gemm_f16(const _Float16* __restrict__ A,
                                                  const _Float16* __restrict__ Wth,
                                                  const _Float16* __restrict__ Wtl,
                                                  const float* __restrict__ dinv,
                                                  _Float16* __restrict__ Hh, int N) {
    const int tid = threadIdx.x;
    const int wave = tid >> 6;
    const int l = tid & 63;
    const int wrow = wave & 1;
    const int wcol = wave >> 1;
    const int lr = l & 15;
    const int lkb = (l >> 4) * 8;

    const int row_base = blockIdx.x * 64 + wrow * 32;
    const int c_base = wcol * 64;

    f32x4 acch[2][4], accl[2][4];
#pragma unroll
    for (int rt = 0; rt < 2; ++rt)
#pragma unroll
        for (int ct = 0; ct < 4; ++ct) {
            acch[rt][ct] = (f32x4){0.f, 0.f, 0.f, 0.f};
            accl[rt][ct] = (f32x4){0.f, 0.f, 0.f, 0.f};
        }

#pragma unroll
    for (int ks = 0; ks < 4; ++ks) {
        const int koff = ks * 32 + lkb;

        half8 bh[4], bl[4];
#pragma unroll
        for (int ct = 0; ct < 4; ++ct) {
            size_t off = (size_t)(c_base + ct * 16 + lr) * 128 + koff;
            bh[ct] = *(const half8*)(Wth + off);
            bl[ct] = *(const half8*)(Wtl + off);
        }

        half8 a[2];
#pragma unroll
        for (int rt = 0; rt < 2; ++rt) {
            int r = row_base + rt * 16 + lr;
            if (r >= N) r = N - 1;                 // clamp; stores guarded
            a[rt] = *(const half8*)(A + (size_t)r * 128 + koff);
        }

#pragma unroll
        for (int rt = 0; rt < 2; ++rt)
#pragma unroll
            for (int ct = 0; ct < 4; ++ct) {
                acch[rt][ct] = __builtin_amdgcn_mfma_f32_16x16x32_f16(a[rt], bh[ct], acch[rt][ct], 0, 0, 0);
                accl[rt][ct] = __builtin_amdgcn_mfma_f32_16x16x32_f16(a[rt], bl[ct], accl[rt][ct], 0, 0, 0);
            }
    }

#pragma unroll
    for (int rt = 0; rt < 2; ++rt) {
        int r0 = row_base + rt * 16 + (l >> 4) * 4;
        float dv[4];
#pragma unroll
        for (int j = 0; j < 4; ++j) dv[j] = (r0 + j < N) ? dinv[r0 + j] : 0.f;
#pragma unroll
        for (int ct = 0; ct < 4; ++ct) {
            int col = c_base + ct * 16 + lr;
#pragma unroll
            for (int j = 0; j < 4; ++j) {
                int r = r0 + j;
                if (r < N) {
                    float v = fmaf(accl[rt][ct][j], LO_INV, acch[rt][ct][j]);
                    Hh[(size_t)r * 128 + col] = (_Float16)(v * dv[j]);
                }
            }
        }
    }
}

// --- aggregate (CSR gather, fp16 rows): one wave per dst node -----------------
__global__ __launch_bounds__(256) void k_aggregate_f16(const int* __restrict__ csr_src,
                                                       const int* __restrict__ rowptr,
                                                       const float* __restrict__ dinv,
                                                       const _Float16* __restrict__ Hh,
                                                       const float* __restrict__ bias,
                                                       _Float16* __restrict__ Ah, int N) {
    int d = blockIdx.x * 4 + (threadIdx.x >> 6);
    if (d >= N) return;
    const int lane = threadIdx.x & 63;
    const unsigned* Hu = (const unsigned*)Hh;        // 64 dwords per row

    int beg = rowptr[d], end = rowptr[d + 1];
    union PK { unsigned u; _Float16 h[2]; };

    PK sv; sv.u = Hu[(size_t)d * 64 + lane];
    float ax = (float)sv.h[0];
    float ay = (float)sv.h[1];

    int j = beg;
    for (; j + 7 < end; j += 8) {
        int s[8]; PK v[8];
#pragma unroll
        for (int u = 0; u < 8; ++u) s[u] = csr_src[j + u];
#pragma unroll
        for (int u = 0; u < 8; ++u) v[u].u = Hu[(size_t)s[u] * 64 + lane];
#pragma unroll
        for (int u = 0; u < 8; ++u) {
            ax += (float)v[u].h[0];
            ay += (float)v[u].h[1];
        }
    }
    for (; j < end; ++j) {
        PK v; v.u = Hu[(size_t)csr_src[j] * 64 + lane];
        ax += (float)v.h[0];
        ay += (float)v.h[1];
    }

    float dd = dinv[d];
    float2 b2 = ((const float2*)bias)[lane];
    ax = fmaxf(fmaf(dd, ax, b2.x), 0.f);
    ay = fmaxf(fmaf(dd, ay, b2.y), 0.f);

    PK o; o.h[0] = (_Float16)ax; o.h[1] = (_Float16)ay;
    ((unsigned*)Ah)[(size_t)d * 64 + lane] = o.u;
}

// --- pool: pooled[g] += A[i] (bias+relu already applied), batch sorted --------
__global__ __launch_bounds__(128) void k_pool(const _Float16* __restrict__ A,
                                              const int* __restrict__ batch,
                                              float* __restrict__ pooled,
                                              float* __restrict__ counts, int N) {
    int k = threadIdx.x;
    int i0 = blockIdx.x * 64;
    if (i0 >= N) return;
    int iend = min(i0 + 64, N);
    float acc = 0.f;
    int cnt = 0;
    int cur = batch[i0];
    for (int i = i0; i < iend; ++i) {
        int g = batch[i];
        if (g != cur) {
            ATOMIC_ADD_F32(&pooled[cur * 128 + k], acc);
            if (k == 0) ATOMIC_ADD_F32(&counts[cur], (float)cnt);
            acc = 0.f; cnt = 0; cur = g;
        }
        acc += (float)A[(size_t)i * 128 + k];
        cnt++;
    }
    ATOMIC_ADD_F32(&pooled[cur * 128 + k], acc);
    if (k == 0) ATOMIC_ADD_F32(&counts[cur], (float)cnt);
}

// --- finalize: global_mean + head ---------------------------------------------
__global__ __launch_bounds__(128) void k_finalize(const float* __restrict__ pooled,
                                                  const float* __restrict__ counts,
                                                  const float* __restrict__ Wl,
                                                  const float* __restrict__ bl,
                                                  float* __restrict__ out) {
    int g = blockIdx.x;
    int t = threadIdx.x;
    __shared__ float m[128];
    float c = fmaxf(counts[g], 1.f);
    float mean = pooled[g * 128 + t] / c;
    out[NG * 10 + g * 128 + t] = mean;
    m[t] = mean;
    __syncthreads();
    if (t < 10) {
        float acc = bl[t];
#pragma unroll 16
        for (int k = 0; k < 128; ++k) acc = fmaf(m[k], Wl[k * 10 + t], acc);
        out[g * 10 + t] = acc;
    }
}

// ---------------------------------------------------------------------------
extern "C" void kernel_launch(void* const* d_in, const int* in_sizes, int n_in,
                              void* d_out, int out_size, void* d_ws, size_t ws_size,
                              hipStream_t stream) {
    const float* x     = (const float*)d_in[0];
    const int*   ei    = (const int*)d_in[1];
    const int*   batch = (const int*)d_in[2];
    const float* Wt[4] = { (const float*)d_in[3], (const float*)d_in[5],
                           (const float*)d_in[7], (const float*)d_in[9] };
    const float* bt[4] = { (const float*)d_in[4], (const float*)d_in[6],
                           (const float*)d_in[8], (const float*)d_in[10] };
    const float* Wl = (const float*)d_in[11];
    const float* bl = (const float*)d_in[12];
    float* out = (float*)d_out;

    const int N = in_sizes[0] / 128;
    const int E = in_sizes[1] / 2;
    const int* src = ei;
    const int* dst = ei + E;

    // workspace layout
    char* p = (char*)d_ws;
    _Float16* Xh    = (_Float16*)p;  p += (size_t)N * 128 * 2;
    _Float16* Hh    = (_Float16*)p;  p += (size_t)N * 128 * 2;
    _Float16* Ah    = (_Float16*)p;  p += (size_t)N * 128 * 2;
    float* dinv     = (float*)p;     p += (size_t)N * 4;
    int*   deg      = (int*)p;       p += (size_t)N * 4;
    int*   rowptr   = (int*)p;       p += (size_t)(N + 1) * 4;
    int*   cursor   = (int*)p;       p += (size_t)N * 4;
    int*   csr_src  = (int*)p;       p += (size_t)E * 4;
    int*   partials = (int*)p;       p += 512 * 4;
    float* pooled   = (float*)p;     p += (size_t)NG * 128 * 4;
    float* counts   = (float*)p;     p += (size_t)NG * 4;
    _Float16* Wsp   = (_Float16*)p;  p += 4 * 2 * 128 * 128 * 2;

    const int nblk = (N + 255) / 256;

    // degrees + norms (XCD-partitioned histogram)
    k_deg_init<<<nblk, 256, 0, stream>>>(deg, N);
    k_deg_count_xcd<<<2048, 256, 0, stream>>>(dst, deg, E, N);

    // CSR build (by dst), scan fused with dinv + cursor seed
    k_scan_local<<<nblk, 256, 0, stream>>>(deg, rowptr, partials, dinv, N);
    k_scan_partials<<<1, 512, 0, stream>>>(partials, nblk);
    k_scan_apply<<<nblk, 256, 0, stream>>>(deg, rowptr, cursor, partials, N);
    k_csr_fill_xcd<<<2048, 256, 0, stream>>>(src, dst, cursor, csr_src, E, N);

    // weight splits (one launch) + X cast
    WSplitArgs wa;
    _Float16* Wth[4]; _Float16* Wtl[4];
    for (int l = 0; l < 4; ++l) {
        Wth[l] = Wsp + (size_t)l * 2 * 16384;
        Wtl[l] = Wth[l] + 16384;
        wa.W[l] = Wt[l];
        wa.Wth[l] = Wth[l];
        wa.Wtl[l] = Wtl[l];
    }
    k_wsplit4<<<256, 256, 0, stream>>>(wa);
    k_xhalf<<<(N * 128 / 4 + 255) / 256, 256, 0, stream>>>(x, Xh, N * 128);

    // layers
    const int gemm_blocks = (N + 63) / 64;
    const int agg_blocks = (N + 3) / 4;
    const _Float16* in = Xh;
    for (int l = 0; l < 4; ++l) {
        k_gemm_f16<<<gemm_blocks, 256, 0, stream>>>(in, Wth[l], Wtl[l], dinv, Hh, N);
        k_aggregate_f16<<<agg_blocks, 256, 0, stream>>>(csr_src, rowptr, dinv, Hh, bt[l], Ah, N);
        in = Ah;
    }

    // pool + head
    hipMemsetAsync(pooled, 0, (size_t)(NG * 128 + NG) * 4, stream);
    k_pool<<<(N + 63) / 64, 128, 0, stream>>>(Ah, batch, pooled, counts, N);
    k_finalize<<<NG, 128, 0, stream>>>(pooled, counts, Wl, bl, out);
}